// Round 1
// baseline (727.895 us; speedup 1.0000x reference)
//
#include <hip/hip_runtime.h>

#define NB    32
#define NMAPS 1024
#define FDIM  512
#define NPOOL 256
#define MT    32      // rows per block tile
#define KT    16      // k-chunk
#define TPB   512     // 8 waves

// 16B-chunk XOR swizzle within a 1024-float row (256 chunks): bijective involution.
__device__ __forceinline__ int swz(int c) { return c ^ ((c >> 3) & 7); }

// Fully-unrolled descending bitonic sort of 4 independent 1024-element rows.
// Element index e = 16*lane + t; V[mi][t] holds row mi's element e.
// Rule: take_min(e) = ((e&k)!=0) == ((e&j)==0)   (descending overall)
__device__ __forceinline__ void sort4_desc(float (&V)[4][16], const int lane) {
#pragma unroll
  for (int kb = 1; kb <= 10; ++kb) {
    const int k = 1 << kb;
#pragma unroll
    for (int jb = 9; jb >= 0; --jb) {
      if (jb >= kb) continue;           // resolved at compile time after unroll
      const int j = 1 << jb;
      if (jb >= 4) {
        // cross-lane stage: partner lane = lane ^ (j>>4), same t. k >= 32 here.
        const int jl = j >> 4;
        const bool tmin = ((lane & (k >> 4)) != 0) == ((lane & jl) == 0);
#pragma unroll
        for (int t = 0; t < 16; ++t) {
#pragma unroll
          for (int mi = 0; mi < 4; ++mi) {
            const float o  = __shfl_xor(V[mi][t], jl, 64);
            const float mn = fminf(V[mi][t], o);
            const float mx = fmaxf(V[mi][t], o);
            V[mi][t] = tmin ? mn : mx;
          }
        }
      } else {
        // in-lane stage: pair (t, t|j)
#pragma unroll
        for (int t = 0; t < 16; ++t) {
          if (t & j) continue;
          const int u = t | j;
          const bool tm = ((((lane << 4) | t) & k) != 0);  // low elem takes min?
#pragma unroll
          for (int mi = 0; mi < 4; ++mi) {
            const float xv = V[mi][t], yv = V[mi][u];
            const float mn = fminf(xv, yv), mx = fmaxf(xv, yv);
            V[mi][t] = tm ? mn : mx;
            V[mi][u] = tm ? mx : mn;
          }
        }
      }
    }
  }
}

__global__ __launch_bounds__(TPB) void corr_pool_kernel(const float* __restrict__ x,
                                                        float* __restrict__ out) {
  __shared__ float lds_a[MT * KT];       // [32][16] A chunk
  __shared__ float lds_bT[KT * NMAPS];   // [16][1024] B chunk, transposed + swizzled

  // Bijective XCD swizzle (1024 blocks, 1024 % 8 == 0): contiguous work per XCD.
  const int bid  = blockIdx.x;
  const int wk   = (bid & 7) * 128 + (bid >> 3);
  const int b    = wk >> 5;
  const int mt   = wk & 31;
  const int M0   = mt * MT;

  const int tid  = threadIdx.x;
  const int lane = tid & 63;
  const int wv   = tid >> 6;

  const float* __restrict__ xb = x + (size_t)b * (NMAPS * FDIM);

  // Register corr tile: rows 4*wv+mi, cols n = 16*lane + ni
  float acc[4][16];
#pragma unroll
  for (int mi = 0; mi < 4; ++mi)
#pragma unroll
    for (int ni = 0; ni < 16; ++ni) acc[mi][ni] = 0.f;

  for (int k0 = 0; k0 < FDIM; k0 += KT) {
    // ---- stage A chunk: 32 rows x 16 k
    {
      const int row = tid >> 4, col = tid & 15;
      lds_a[tid] = xb[(M0 + row) * FDIM + k0 + col];
    }
    // ---- stage B chunk transposed: lds_bT[k][n], n swizzled per 16B chunk
#pragma unroll
    for (int it = 0; it < 8; ++it) {
      const int idx = it * TPB + tid;       // 0..4095 -> (n, q)
      const int n = idx >> 2, q = idx & 3;
      const float4 v = *(const float4*)(xb + n * FDIM + k0 + q * 4);
      const int colp = swz(n >> 2) * 4 + (n & 3);
      lds_bT[(q * 4 + 0) * NMAPS + colp] = v.x;
      lds_bT[(q * 4 + 1) * NMAPS + colp] = v.y;
      lds_bT[(q * 4 + 2) * NMAPS + colp] = v.z;
      lds_bT[(q * 4 + 3) * NMAPS + colp] = v.w;
    }
    __syncthreads();

    // ---- compute
#pragma unroll
    for (int kk4 = 0; kk4 < KT / 4; ++kk4) {
      float aR[4][4];
#pragma unroll
      for (int mi = 0; mi < 4; ++mi) {
        const float4 t4 = *(const float4*)(lds_a + (4 * wv + mi) * KT + kk4 * 4);
        aR[mi][0] = t4.x; aR[mi][1] = t4.y; aR[mi][2] = t4.z; aR[mi][3] = t4.w;
      }
#pragma unroll
      for (int dk = 0; dk < 4; ++dk) {
        const int kk = kk4 * 4 + dk;
        float bv[16];
#pragma unroll
        for (int r = 0; r < 4; ++r) {
          const float4 t4 = *(const float4*)(lds_bT + kk * NMAPS + swz(4 * lane + r) * 4);
          bv[4 * r + 0] = t4.x; bv[4 * r + 1] = t4.y;
          bv[4 * r + 2] = t4.z; bv[4 * r + 3] = t4.w;
        }
#pragma unroll
        for (int mi = 0; mi < 4; ++mi)
#pragma unroll
          for (int ni = 0; ni < 16; ++ni)
            acc[mi][ni] += aR[mi][dk] * bv[ni];
      }
    }
    __syncthreads();   // also protects lds_bT before sort-phase reuse
  }

  // ---- scale by 1/F (exact: power of two)
#pragma unroll
  for (int mi = 0; mi < 4; ++mi)
#pragma unroll
    for (int ni = 0; ni < 16; ++ni) acc[mi][ni] *= (1.0f / 512.0f);

  // ---- ranks for this lane's 4 outputs (i = 4*lane + q)
  int rk[4];
#pragma unroll
  for (int q = 0; q < 4; ++q) {
    const int i_out = lane * 4 + q;
    const double v = 1.0 + (double)i_out * (1022.0 / 255.0);
    rk[q] = (int)(v + 0.5);   // verified: never within 1e-3 of a .5 boundary
  }

  // ---- per-wave in-register sort of 4 rows (descending)
  sort4_desc(acc, lane);

  // ---- per row: dump to per-wave swizzled LDS buffer, gather ranks, store
  float* const sbuf = lds_bT + wv * NMAPS;   // 4KB per wave, disjoint regions
#pragma unroll
  for (int mi = 0; mi < 4; ++mi) {
#pragma unroll
    for (int r = 0; r < 4; ++r) {
      *(float4*)(sbuf + swz(4 * lane + r) * 4) =
          make_float4(acc[mi][4 * r + 0], acc[mi][4 * r + 1],
                      acc[mi][4 * r + 2], acc[mi][4 * r + 3]);
    }
    float ov[4];
#pragma unroll
    for (int q = 0; q < 4; ++q) {
      const int s = rk[q];
      ov[q] = sbuf[swz(s >> 2) * 4 + (s & 3)];
    }
    const int m = M0 + 4 * wv + mi;
    float4* const op = (float4*)(out + ((size_t)b * NMAPS + m) * NPOOL);
    op[lane] = make_float4(ov[0], ov[1], ov[2], ov[3]);
  }
}

extern "C" void kernel_launch(void* const* d_in, const int* in_sizes, int n_in,
                              void* d_out, int out_size, void* d_ws, size_t ws_size,
                              hipStream_t stream) {
  const float* x = (const float*)d_in[0];
  float* out = (float*)d_out;
  corr_pool_kernel<<<dim3(NB * (NMAPS / MT)), dim3(TPB), 0, stream>>>(x, out);
}

// Round 2
// 305.181 us; speedup vs baseline: 2.3851x; 2.3851x over previous
//
#include <hip/hip_runtime.h>

#define NB    32
#define NMAPS 1024
#define FDIM  512
#define NPOOL 256
#define TPB   512   // 8 waves

typedef short  bf16x8 __attribute__((ext_vector_type(8)));
typedef float  f32x4  __attribute__((ext_vector_type(4)));

// f32 -> bf16, round-to-nearest-even (truncation would bias the dot ~3e-3)
__device__ __forceinline__ unsigned short f2bf(float f) {
  unsigned int u = __float_as_uint(f);
  return (unsigned short)((u + 0x7fffu + ((u >> 16) & 1u)) >> 16);
}

__global__ __launch_bounds__(256) void convert_kernel(const float* __restrict__ x,
                                                      unsigned short* __restrict__ xb) {
  const size_t i = ((size_t)blockIdx.x * 256 + threadIdx.x) * 8;
  const float4 p = *(const float4*)(x + i);
  const float4 q = *(const float4*)(x + i + 4);
  uint4 o;
  o.x = (unsigned)f2bf(p.x) | ((unsigned)f2bf(p.y) << 16);
  o.y = (unsigned)f2bf(p.z) | ((unsigned)f2bf(p.w) << 16);
  o.z = (unsigned)f2bf(q.x) | ((unsigned)f2bf(q.y) << 16);
  o.w = (unsigned)f2bf(q.z) | ((unsigned)f2bf(q.w) << 16);
  *(uint4*)(xb + i) = o;
}

__device__ __forceinline__ bf16x8 ld_frag_f32(const float* p) {
  const float4 a = *(const float4*)p;
  const float4 b = *(const float4*)(p + 4);
  bf16x8 r;
  r[0] = (short)f2bf(a.x); r[1] = (short)f2bf(a.y);
  r[2] = (short)f2bf(a.z); r[3] = (short)f2bf(a.w);
  r[4] = (short)f2bf(b.x); r[5] = (short)f2bf(b.y);
  r[6] = (short)f2bf(b.z); r[7] = (short)f2bf(b.w);
  return r;
}

// Exchange-buffer swizzle: <=2-way banks for both the MFMA-side write
// (lanes vary col bits0-3 & row) and the sort-side read (lanes vary col
// bits6-9 & row low bits). Bijective per row (XOR of bits 0-4 keyed on
// bits >=6 of col and bits of row).
__device__ __forceinline__ int swz_ex(int row, int col) {
  return col ^ (((col >> 6) & 15) << 1) ^ (row & 1) ^ (((row >> 2) & 1) << 4);
}

// Descending bitonic sort of a 1024-element row spread over 16 lanes
// (li = lane&15), 64 elems/lane: position e = 64*li + t.
// take_min(low elem) = ((e&k)!=0) == ((e&j)==0)  (verified in round 1).
__device__ __forceinline__ void sort1024_desc(float (&v)[64], const int li) {
#pragma unroll
  for (int kb = 1; kb <= 10; ++kb) {
    const int k = 1 << kb;
#pragma unroll
    for (int jb = 9; jb >= 0; --jb) {
      if (jb >= kb) continue;          // folds at compile time
      const int j = 1 << jb;
      if (jb >= 6) {
        // cross-lane: partner li ^ (j>>6), same t (stays within the 16-lane group)
        const int jl = j >> 6;
        const bool up = (li & (k >> 6)) != 0;   // e&k != 0  (k >= 128 here)
        const bool tm = up == ((li & jl) == 0); // this elem keeps min?
#pragma unroll
        for (int t = 0; t < 64; ++t) {
          const float o  = __shfl_xor(v[t], jl, 64);
          const float mn = fminf(v[t], o);
          const float mx = fmaxf(v[t], o);
          v[t] = tm ? mn : mx;
        }
      } else if (kb <= 5) {
        // in-lane, direction known at compile time (e&k = t&k)
#pragma unroll
        for (int t = 0; t < 64; ++t) {
          if (t & j) continue;
          const int u = t | j;
          const float a0 = v[t], b0 = v[u];
          if ((t & k) != 0) { v[t] = fminf(a0, b0); v[u] = fmaxf(a0, b0); }
          else              { v[t] = fmaxf(a0, b0); v[u] = fminf(a0, b0); }
        }
      } else {
        // in-lane, direction uniform per lane (e&k = 64*(li & (k>>6)))
        const bool tm = (li & (k >> 6)) != 0;
#pragma unroll
        for (int t = 0; t < 64; ++t) {
          if (t & j) continue;
          const int u = t | j;
          const float a0 = v[t], b0 = v[u];
          const float mn = fminf(a0, b0), mx = fmaxf(a0, b0);
          v[t] = tm ? mn : mx;
          v[u] = tm ? mx : mn;
        }
      }
    }
  }
}

template <bool WS>
__global__ __launch_bounds__(TPB) void corr_pool_kernel(const float* __restrict__ x,
                                                        const unsigned short* __restrict__ xbf,
                                                        float* __restrict__ out) {
  __shared__ float ex[16 * 1024];   // 64 KiB exchange buffer -> 2 blocks/CU

  // XCD-locality mapping: all 32 row-tiles of a batch land on one XCD
  // (bid%8 round-robin assumption; perf-only if wrong).
  const int bid = blockIdx.x;
  const int xcd = bid & 7;
  const int idx = bid >> 3;              // 0..127
  const int b   = xcd + 8 * (idx >> 5);  // batch
  const int M0  = (idx & 31) * 32;       // row-tile base

  const int tid  = threadIdx.x;
  const int lane = tid & 63;
  const int w    = tid >> 6;   // wave 0..7: owns cols [128w,128w+128)
  const int li   = lane & 15;
  const int kh   = lane >> 4;  // k-block selector for MFMA frags

  const size_t base = (size_t)b * NMAPS * FDIM;
  const float* __restrict__ Xf = x + base;
  const unsigned short* __restrict__ Xb = WS ? (xbf + base) : (const unsigned short*)nullptr;

  // ---------------- GEMM: 32 rows x 1024 cols, bf16 MFMA, no LDS, no barriers
  f32x4 acc[2][8];
#pragma unroll
  for (int a = 0; a < 2; ++a)
#pragma unroll
    for (int n = 0; n < 8; ++n) acc[a][n] = (f32x4){0.f, 0.f, 0.f, 0.f};

#pragma unroll 2
  for (int k0 = 0; k0 < FDIM; k0 += 32) {
    bf16x8 A[2], B[8];
#pragma unroll
    for (int a = 0; a < 2; ++a) {
      const int off = (M0 + 16 * a + li) * FDIM + k0 + kh * 8;
      if (WS) A[a] = *(const bf16x8*)(Xb + off);
      else    A[a] = ld_frag_f32(Xf + off);
    }
#pragma unroll
    for (int n = 0; n < 8; ++n) {
      const int off = (128 * w + 16 * n + li) * FDIM + k0 + kh * 8;
      if (WS) B[n] = *(const bf16x8*)(Xb + off);
      else    B[n] = ld_frag_f32(Xf + off);
    }
#pragma unroll
    for (int a = 0; a < 2; ++a)
#pragma unroll
      for (int n = 0; n < 8; ++n)
        acc[a][n] = __builtin_amdgcn_mfma_f32_16x16x32_bf16(A[a], B[n], acc[a][n], 0, 0, 0);
  }

  // ---------------- exchange: MFMA frag layout -> 4 rows/wave, 64 elems/lane
  const int R = 4 * w + kh;   // the block-row this lane will sort
  float v[64];

#pragma unroll
  for (int p = 0; p < 2; ++p) {    // row halves 0..15 / 16..31
#pragma unroll
    for (int n = 0; n < 8; ++n) {
      const int col = 128 * w + 16 * n + li;
#pragma unroll
      for (int r = 0; r < 4; ++r) {
        const int row = 16 * p + 4 * kh + r;   // C layout: row=(lane>>4)*4+reg
        ex[(row & 15) * 1024 + swz_ex(row, col)] = acc[p][n][r] * (1.0f / FDIM);
      }
    }
    __syncthreads();
    if ((w >> 2) == p) {
#pragma unroll
      for (int t = 0; t < 64; ++t)
        v[t] = ex[(R & 15) * 1024 + swz_ex(R, 64 * li + t)];
    }
    __syncthreads();
  }

  // ---------------- in-register bitonic sort (descending)
  sort1024_desc(v, li);

  // ---------------- rank gather + store (two sub-passes reuse the 64KB buffer)
  __syncthreads();
#pragma unroll
  for (int gp = 0; gp < 2; ++gp) {
    if ((w >> 2) == gp) {
#pragma unroll
      for (int t = 0; t < 64; ++t)
        ex[(R & 15) * 1024 + swz_ex(R, 64 * li + t)] = v[t];
    }
    __syncthreads();
    if ((w >> 2) == gp) {
#pragma unroll
      for (int rp = 0; rp < 4; ++rp) {
        const int Rr = 4 * w + rp;
        float ov[4];
#pragma unroll
        for (int q = 0; q < 4; ++q) {
          const int i = 4 * lane + q;
          const double dv = 1.0 + (double)i * (1022.0 / 255.0); // exact-safe ranks
          const int s = (int)(dv + 0.5);
          ov[q] = ex[(Rr & 15) * 1024 + swz_ex(Rr, s)];
        }
        float* op = out + (size_t)(b * NMAPS + M0 + Rr) * NPOOL;
        *(float4*)(op + 4 * lane) = make_float4(ov[0], ov[1], ov[2], ov[3]);
      }
    }
    __syncthreads();
  }
}

extern "C" void kernel_launch(void* const* d_in, const int* in_sizes, int n_in,
                              void* d_out, int out_size, void* d_ws, size_t ws_size,
                              hipStream_t stream) {
  const float* x = (const float*)d_in[0];
  float* out = (float*)d_out;
  const size_t need = (size_t)NB * NMAPS * FDIM * sizeof(unsigned short);  // 33.5 MB
  if (ws_size >= need) {
    unsigned short* xb = (unsigned short*)d_ws;
    convert_kernel<<<dim3((NB * NMAPS * FDIM) / (256 * 8)), dim3(256), 0, stream>>>(x, xb);
    corr_pool_kernel<true><<<dim3(NB * 32), dim3(TPB), 0, stream>>>(x, xb, out);
  } else {
    corr_pool_kernel<false><<<dim3(NB * 32), dim3(TPB), 0, stream>>>(x, nullptr, out);
  }
}

// Round 3
// 288.378 us; speedup vs baseline: 2.5241x; 1.0583x over previous
//
#include <hip/hip_runtime.h>

#define NB    32
#define NMAPS 1024
#define FDIM  512
#define NPOOL 256

typedef short  bf16x8 __attribute__((ext_vector_type(8)));
typedef float  f32x4  __attribute__((ext_vector_type(4)));

// f32 -> bf16 round-to-nearest-even
__device__ __forceinline__ unsigned short f2bf(float f) {
  unsigned int u = __float_as_uint(f);
  return (unsigned short)((u + 0x7fffu + ((u >> 16) & 1u)) >> 16);
}

// 16B-chunk XOR swizzle within a 1024-float row (256 chunks); involution.
__device__ __forceinline__ int swz(int c) { return c ^ ((c >> 3) & 7); }

// exact ranks: round(1 + o*1022/255) = (765 + 2044*o) / 510  (integer div)
__device__ __forceinline__ int rank_of(int o) { return (765 + 2044 * o) / 510; }

__global__ __launch_bounds__(256) void convert_kernel(const float* __restrict__ x,
                                                      unsigned short* __restrict__ xb) {
  const size_t i = ((size_t)blockIdx.x * 256 + threadIdx.x) * 8;
  const float4 p = *(const float4*)(x + i);
  const float4 q = *(const float4*)(x + i + 4);
  uint4 o;
  o.x = (unsigned)f2bf(p.x) | ((unsigned)f2bf(p.y) << 16);
  o.y = (unsigned)f2bf(p.z) | ((unsigned)f2bf(p.w) << 16);
  o.z = (unsigned)f2bf(q.x) | ((unsigned)f2bf(q.y) << 16);
  o.w = (unsigned)f2bf(q.z) | ((unsigned)f2bf(q.w) << 16);
  *(uint4*)(xb + i) = o;
}

// ---------------- standalone GEMM: C[b] = Xb * Xb^T / 512  (f32 out)
__global__ __launch_bounds__(512, 4) void gemm_kernel(const unsigned short* __restrict__ xb,
                                                      float* __restrict__ C) {
  const int bid = blockIdx.x;
  const int xcd = bid & 7;
  const int idx = bid >> 3;
  const int b   = xcd + 8 * (idx >> 5);   // 4 batches per XCD: B-panel L2-resident
  const int M0  = (idx & 31) * 32;

  const int tid = threadIdx.x, lane = tid & 63, w = tid >> 6;
  const int li  = lane & 15,  kh = lane >> 4;   // frag row/col = li, k-chunk = kh (0..3)

  const unsigned short* __restrict__ Xb = xb + (size_t)b * NMAPS * FDIM;

  f32x4 acc[2][8];
#pragma unroll
  for (int a = 0; a < 2; ++a)
#pragma unroll
    for (int n = 0; n < 8; ++n) acc[a][n] = (f32x4){0.f, 0.f, 0.f, 0.f};

#pragma unroll 2
  for (int k0 = 0; k0 < FDIM; k0 += 32) {
    bf16x8 A[2], B[8];
#pragma unroll
    for (int a = 0; a < 2; ++a)
      A[a] = *(const bf16x8*)(Xb + (M0 + 16 * a + li) * FDIM + k0 + kh * 8);
#pragma unroll
    for (int n = 0; n < 8; ++n)
      B[n] = *(const bf16x8*)(Xb + (128 * w + 16 * n + li) * FDIM + k0 + kh * 8);
#pragma unroll
    for (int a = 0; a < 2; ++a)
#pragma unroll
      for (int n = 0; n < 8; ++n)
        acc[a][n] = __builtin_amdgcn_mfma_f32_16x16x32_bf16(A[a], B[n], acc[a][n], 0, 0, 0);
  }

  // C/D layout (m89): col = lane&15, row = (lane>>4)*4 + reg  (C symmetric anyway)
  float* __restrict__ Cb = C + ((size_t)b * NMAPS + M0) * NMAPS;
#pragma unroll
  for (int a = 0; a < 2; ++a)
#pragma unroll
    for (int n = 0; n < 8; ++n)
#pragma unroll
      for (int r = 0; r < 4; ++r)
        Cb[(16 * a + 4 * kh + r) * NMAPS + 128 * w + 16 * n + li] =
            acc[a][n][r] * (1.0f / 512.0f);
}

// ---------------- sort + percentile gather: 8 rows/block, 32 lanes x 32 elems per row
__global__ __launch_bounds__(256) void sort_kernel(const float* __restrict__ C,
                                                   float* __restrict__ out) {
  __shared__ float buf[8 * NMAPS];   // 32 KiB
  const int tid  = threadIdx.x;
  const int lane = tid & 63;
  const int wv   = tid >> 6;
  const int ll   = lane & 31;        // lane within row-group
  const int h    = lane >> 5;        // which of the wave's 2 rows
  const int rloc = wv * 2 + h;
  const size_t row = (size_t)blockIdx.x * 8 + rloc;

  // load: element e = 32*ll + t
  float v[32];
  {
    const float* rp = C + row * NMAPS + 32 * ll;
#pragma unroll
    for (int i = 0; i < 8; ++i) {
      const float4 t4 = *(const float4*)(rp + 4 * i);
      v[4 * i + 0] = t4.x; v[4 * i + 1] = t4.y;
      v[4 * i + 2] = t4.z; v[4 * i + 3] = t4.w;
    }
  }

  // descending bitonic sort of 1024 elems: take_min(e) = ((e&k)!=0)==((e&j)==0)
#pragma unroll
  for (int kb = 1; kb <= 10; ++kb) {
    const int k = 1 << kb;
#pragma unroll
    for (int jb = 9; jb >= 0; --jb) {
      if (jb >= kb) continue;        // folds at compile time
      const int j = 1 << jb;
      if (jb >= 5) {
        // cross-lane: partner ll ^ (j>>5) (stays in 32-lane group, h preserved)
        const int jl = j >> 5;
        const bool up = (ll & (k >> 5)) != 0;     // e&k  (kb>=6 here)
        const bool tm = up == ((ll & jl) == 0);
#pragma unroll
        for (int t = 0; t < 32; ++t) {
          const float o  = __shfl_xor(v[t], jl, 64);
          const float mn = fminf(v[t], o);
          const float mx = fmaxf(v[t], o);
          v[t] = tm ? mn : mx;
        }
      } else if (kb <= 4) {
        // in-lane, direction compile-time (e&k = t&k since k<=16)
#pragma unroll
        for (int t = 0; t < 32; ++t) {
          if (t & j) continue;
          const int u = t | j;
          const float a0 = v[t], b0 = v[u];
          if ((t & k) != 0) { v[t] = fminf(a0, b0); v[u] = fmaxf(a0, b0); }
          else              { v[t] = fmaxf(a0, b0); v[u] = fminf(a0, b0); }
        }
      } else {
        // in-lane, direction uniform per lane (e&k = (ll & (k>>5)) << 5)
        const bool tm = (ll & (k >> 5)) != 0;
#pragma unroll
        for (int t = 0; t < 32; ++t) {
          if (t & j) continue;
          const int u = t | j;
          const float a0 = v[t], b0 = v[u];
          const float mn = fminf(a0, b0), mx = fmaxf(a0, b0);
          v[t] = tm ? mn : mx;
          v[u] = tm ? mx : mn;
        }
      }
    }
  }

  // dump sorted row to LDS (swizzled 16B chunks), then gather ranks
  {
    float* sb = buf + rloc * NMAPS;
#pragma unroll
    for (int i = 0; i < 8; ++i)
      *(float4*)(sb + swz(8 * ll + i) * 4) =
          make_float4(v[4 * i + 0], v[4 * i + 1], v[4 * i + 2], v[4 * i + 3]);
  }
  __syncthreads();

#pragma unroll
  for (int h2 = 0; h2 < 2; ++h2) {
    const float* sb2 = buf + (wv * 2 + h2) * NMAPS;
    const size_t row2 = (size_t)blockIdx.x * 8 + wv * 2 + h2;
    float ov[4];
#pragma unroll
    for (int q = 0; q < 4; ++q) {
      const int s = rank_of(4 * lane + q);
      ov[q] = sb2[swz(s >> 2) * 4 + (s & 3)];
    }
    *(float4*)(out + row2 * NPOOL + 4 * lane) =
        make_float4(ov[0], ov[1], ov[2], ov[3]);
  }
}

// ================= fallback fused kernel (round-2, used only if ws too small) =================
__device__ __forceinline__ bf16x8 ld_frag_f32(const float* p) {
  const float4 a = *(const float4*)p;
  const float4 b = *(const float4*)(p + 4);
  bf16x8 r;
  r[0] = (short)f2bf(a.x); r[1] = (short)f2bf(a.y);
  r[2] = (short)f2bf(a.z); r[3] = (short)f2bf(a.w);
  r[4] = (short)f2bf(b.x); r[5] = (short)f2bf(b.y);
  r[6] = (short)f2bf(b.z); r[7] = (short)f2bf(b.w);
  return r;
}

__device__ __forceinline__ int swz_ex(int row, int col) {
  return col ^ (((col >> 6) & 15) << 1) ^ (row & 1) ^ (((row >> 2) & 1) << 4);
}

__device__ __forceinline__ void sort1024_desc(float (&v)[64], const int li) {
#pragma unroll
  for (int kb = 1; kb <= 10; ++kb) {
    const int k = 1 << kb;
#pragma unroll
    for (int jb = 9; jb >= 0; --jb) {
      if (jb >= kb) continue;
      const int j = 1 << jb;
      if (jb >= 6) {
        const int jl = j >> 6;
        const bool up = (li & (k >> 6)) != 0;
        const bool tm = up == ((li & jl) == 0);
#pragma unroll
        for (int t = 0; t < 64; ++t) {
          const float o  = __shfl_xor(v[t], jl, 64);
          const float mn = fminf(v[t], o);
          const float mx = fmaxf(v[t], o);
          v[t] = tm ? mn : mx;
        }
      } else if (kb <= 5) {
#pragma unroll
        for (int t = 0; t < 64; ++t) {
          if (t & j) continue;
          const int u = t | j;
          const float a0 = v[t], b0 = v[u];
          if ((t & k) != 0) { v[t] = fminf(a0, b0); v[u] = fmaxf(a0, b0); }
          else              { v[t] = fmaxf(a0, b0); v[u] = fminf(a0, b0); }
        }
      } else {
        const bool tm = (li & (k >> 6)) != 0;
#pragma unroll
        for (int t = 0; t < 64; ++t) {
          if (t & j) continue;
          const int u = t | j;
          const float a0 = v[t], b0 = v[u];
          const float mn = fminf(a0, b0), mx = fmaxf(a0, b0);
          v[t] = tm ? mn : mx;
          v[u] = tm ? mx : mn;
        }
      }
    }
  }
}

template <bool WS>
__global__ __launch_bounds__(512) void corr_pool_kernel(const float* __restrict__ x,
                                                        const unsigned short* __restrict__ xbf,
                                                        float* __restrict__ out) {
  __shared__ float ex[16 * 1024];
  const int bid = blockIdx.x;
  const int xcd = bid & 7;
  const int idx = bid >> 3;
  const int b   = xcd + 8 * (idx >> 5);
  const int M0  = (idx & 31) * 32;

  const int tid  = threadIdx.x;
  const int lane = tid & 63;
  const int w    = tid >> 6;
  const int li   = lane & 15;
  const int kh   = lane >> 4;

  const size_t base = (size_t)b * NMAPS * FDIM;
  const float* __restrict__ Xf = x + base;
  const unsigned short* __restrict__ Xb = WS ? (xbf + base) : (const unsigned short*)nullptr;

  f32x4 acc[2][8];
#pragma unroll
  for (int a = 0; a < 2; ++a)
#pragma unroll
    for (int n = 0; n < 8; ++n) acc[a][n] = (f32x4){0.f, 0.f, 0.f, 0.f};

#pragma unroll 2
  for (int k0 = 0; k0 < FDIM; k0 += 32) {
    bf16x8 A[2], B[8];
#pragma unroll
    for (int a = 0; a < 2; ++a) {
      const int off = (M0 + 16 * a + li) * FDIM + k0 + kh * 8;
      if (WS) A[a] = *(const bf16x8*)(Xb + off);
      else    A[a] = ld_frag_f32(Xf + off);
    }
#pragma unroll
    for (int n = 0; n < 8; ++n) {
      const int off = (128 * w + 16 * n + li) * FDIM + k0 + kh * 8;
      if (WS) B[n] = *(const bf16x8*)(Xb + off);
      else    B[n] = ld_frag_f32(Xf + off);
    }
#pragma unroll
    for (int a = 0; a < 2; ++a)
#pragma unroll
      for (int n = 0; n < 8; ++n)
        acc[a][n] = __builtin_amdgcn_mfma_f32_16x16x32_bf16(A[a], B[n], acc[a][n], 0, 0, 0);
  }

  const int R = 4 * w + kh;
  float v[64];
#pragma unroll
  for (int p = 0; p < 2; ++p) {
#pragma unroll
    for (int n = 0; n < 8; ++n) {
      const int col = 128 * w + 16 * n + li;
#pragma unroll
      for (int r = 0; r < 4; ++r) {
        const int rw = 16 * p + 4 * kh + r;
        ex[(rw & 15) * 1024 + swz_ex(rw, col)] = acc[p][n][r] * (1.0f / FDIM);
      }
    }
    __syncthreads();
    if ((w >> 2) == p) {
#pragma unroll
      for (int t = 0; t < 64; ++t)
        v[t] = ex[(R & 15) * 1024 + swz_ex(R, 64 * li + t)];
    }
    __syncthreads();
  }

  sort1024_desc(v, li);

  __syncthreads();
#pragma unroll
  for (int gp = 0; gp < 2; ++gp) {
    if ((w >> 2) == gp) {
#pragma unroll
      for (int t = 0; t < 64; ++t)
        ex[(R & 15) * 1024 + swz_ex(R, 64 * li + t)] = v[t];
    }
    __syncthreads();
    if ((w >> 2) == gp) {
#pragma unroll
      for (int rp = 0; rp < 4; ++rp) {
        const int Rr = 4 * w + rp;
        float ov[4];
#pragma unroll
        for (int q = 0; q < 4; ++q) {
          const int s = rank_of(4 * lane + q);
          ov[q] = ex[(Rr & 15) * 1024 + swz_ex(Rr, s)];
        }
        float* op = out + (size_t)(b * NMAPS + M0 + Rr) * NPOOL;
        *(float4*)(op + 4 * lane) = make_float4(ov[0], ov[1], ov[2], ov[3]);
      }
    }
    __syncthreads();
  }
}

extern "C" void kernel_launch(void* const* d_in, const int* in_sizes, int n_in,
                              void* d_out, int out_size, void* d_ws, size_t ws_size,
                              hipStream_t stream) {
  const float* x = (const float*)d_in[0];
  float* out = (float*)d_out;
  const size_t bf16_bytes = (size_t)NB * NMAPS * FDIM * sizeof(unsigned short);  // 32 MiB
  const size_t corr_bytes = (size_t)NB * NMAPS * NMAPS * sizeof(float);          // 128 MiB

  if (ws_size >= bf16_bytes + corr_bytes) {
    unsigned short* xb = (unsigned short*)d_ws;
    float* C = (float*)((char*)d_ws + bf16_bytes);
    convert_kernel<<<dim3((NB * NMAPS * FDIM) / (256 * 8)), dim3(256), 0, stream>>>(x, xb);
    gemm_kernel<<<dim3(NB * 32), dim3(512), 0, stream>>>(xb, C);
    sort_kernel<<<dim3(NB * NMAPS / 8), dim3(256), 0, stream>>>(C, out);
  } else if (ws_size >= bf16_bytes) {
    unsigned short* xb = (unsigned short*)d_ws;
    convert_kernel<<<dim3((NB * NMAPS * FDIM) / (256 * 8)), dim3(256), 0, stream>>>(x, xb);
    corr_pool_kernel<true><<<dim3(NB * 32), dim3(512), 0, stream>>>(x, xb, out);
  } else {
    corr_pool_kernel<false><<<dim3(NB * 32), dim3(512), 0, stream>>>(x, nullptr, out);
  }
}

// Round 4
// 222.427 us; speedup vs baseline: 3.2725x; 1.2965x over previous
//
#include <hip/hip_runtime.h>

#define NB    32
#define NMAPS 1024
#define FDIM  512
#define NPOOL 256

typedef short  bf16x8 __attribute__((ext_vector_type(8)));
typedef float  f32x4  __attribute__((ext_vector_type(4)));

// f32 -> bf16 round-to-nearest-even
__device__ __forceinline__ unsigned short f2bf(float f) {
  unsigned int u = __float_as_uint(f);
  return (unsigned short)((u + 0x7fffu + ((u >> 16) & 1u)) >> 16);
}

// 16B-chunk XOR swizzle within a 1024-float row (256 chunks); involution.
__device__ __forceinline__ int swz(int c) { return c ^ ((c >> 3) & 7); }

// exact ranks: round(1 + o*1022/255) = (765 + 2044*o) / 510  (integer div)
__device__ __forceinline__ int rank_of(int o) { return (765 + 2044 * o) / 510; }

// ---------------- convert to FRAGMENT-MAJOR bf16 layout:
// Xp chunk index (((b*64+g)*64+kc)*16+li)*8+e  holds  X[b][16g+li][8kc+e]
// => an MFMA fragment (16 rows of group g, k-chunk kc0..kc0+3) is 1024
//    CONTIGUOUS bytes, lane offset = lane*16B. Perfect coalescing, no LDS.
__global__ __launch_bounds__(256) void convert_perm_kernel(const float* __restrict__ x,
                                                           unsigned short* __restrict__ xp) {
  const int T  = blockIdx.x * 256 + threadIdx.x;  // (b,g,kc,li)
  const int li = T & 15;
  const int kc = (T >> 4) & 63;
  const int g  = (T >> 10) & 63;
  const int b  = T >> 16;
  const float* src = x + ((size_t)((b * 64 + g) * 16 + li) * FDIM + kc * 8);
  const float4 p = *(const float4*)src;
  const float4 q = *(const float4*)(src + 4);
  uint4 o;
  o.x = (unsigned)f2bf(p.x) | ((unsigned)f2bf(p.y) << 16);
  o.y = (unsigned)f2bf(p.z) | ((unsigned)f2bf(p.w) << 16);
  o.z = (unsigned)f2bf(q.x) | ((unsigned)f2bf(q.y) << 16);
  o.w = (unsigned)f2bf(q.z) | ((unsigned)f2bf(q.w) << 16);
  *(uint4*)(xp + (size_t)T * 8) = o;
}

// ---------------- GEMM: 128x128 tile, 4 waves (2x2), direct coalesced loads
__global__ __launch_bounds__(256, 4) void gemm_kernel(const unsigned short* __restrict__ xp,
                                                      float* __restrict__ C) {
  // grid = 2048 = 32 batches * 64 tiles; XCD swizzle: 4 whole batches per XCD
  const int bid = blockIdx.x;
  const int wk  = (bid & 7) * 256 + (bid >> 3);
  const int b   = wk >> 6;
  const int t   = wk & 63;
  const int ti  = t >> 3, tj = t & 7;

  const int tid  = threadIdx.x;
  const int lane = tid & 63;
  const int wr   = (tid >> 6) & 1;
  const int wc   = (tid >> 7) & 1;

  const unsigned short* __restrict__ Xp = xp + (size_t)b * (NMAPS * FDIM);
  const int gA0 = 8 * ti + 4 * wr;   // A row-groups gA0..gA0+3
  const int gB0 = 8 * tj + 4 * wc;   // B row-groups gB0..gB0+3

  f32x4 acc[4][4];
#pragma unroll
  for (int a = 0; a < 4; ++a)
#pragma unroll
    for (int n = 0; n < 4; ++n) acc[a][n] = (f32x4){0.f, 0.f, 0.f, 0.f};

  const unsigned short* pA = Xp + (size_t)gA0 * (64 * 128) + lane * 8;
  const unsigned short* pB = Xp + (size_t)gB0 * (64 * 128) + lane * 8;

  for (int kc0 = 0; kc0 < 64; kc0 += 4) {   // K step 32 (4 chunks of 8)
    bf16x8 A[4], B[4];
#pragma unroll
    for (int a = 0; a < 4; ++a) A[a] = *(const bf16x8*)(pA + a * (64 * 128) + kc0 * 128);
#pragma unroll
    for (int n = 0; n < 4; ++n) B[n] = *(const bf16x8*)(pB + n * (64 * 128) + kc0 * 128);
#pragma unroll
    for (int a = 0; a < 4; ++a)
#pragma unroll
      for (int n = 0; n < 4; ++n)
        acc[a][n] = __builtin_amdgcn_mfma_f32_16x16x32_bf16(A[a], B[n], acc[a][n], 0, 0, 0);
  }

  // C/D layout: col = lane&15, row = (lane>>4)*4 + reg  (C symmetric)
  const int li = lane & 15, kh = lane >> 4;
  float* __restrict__ Cb = C + (size_t)b * NMAPS * NMAPS;
#pragma unroll
  for (int a = 0; a < 4; ++a)
#pragma unroll
    for (int n = 0; n < 4; ++n)
#pragma unroll
      for (int r = 0; r < 4; ++r)
        Cb[(size_t)(128 * ti + 64 * wr + 16 * a + 4 * kh + r) * NMAPS +
           (128 * tj + 64 * wc + 16 * n + li)] = acc[a][n][r] * (1.0f / 512.0f);
}

// ---------------- sort + percentile gather: 8 rows/block, 32 lanes x 32 elems per row
__global__ __launch_bounds__(256) void sort_kernel(const float* __restrict__ C,
                                                   float* __restrict__ out) {
  __shared__ float buf[8 * NMAPS];   // 32 KiB
  const int tid  = threadIdx.x;
  const int lane = tid & 63;
  const int wv   = tid >> 6;
  const int ll   = lane & 31;        // lane within row-group
  const int h    = lane >> 5;        // which of the wave's 2 rows
  const int rloc = wv * 2 + h;
  const size_t row = (size_t)blockIdx.x * 8 + rloc;

  // load: element e = 32*ll + t
  float v[32];
  {
    const float* rp = C + row * NMAPS + 32 * ll;
#pragma unroll
    for (int i = 0; i < 8; ++i) {
      const float4 t4 = *(const float4*)(rp + 4 * i);
      v[4 * i + 0] = t4.x; v[4 * i + 1] = t4.y;
      v[4 * i + 2] = t4.z; v[4 * i + 3] = t4.w;
    }
  }

  // descending bitonic sort of 1024 elems: take_min(e) = ((e&k)!=0)==((e&j)==0)
#pragma unroll
  for (int kb = 1; kb <= 10; ++kb) {
    const int k = 1 << kb;
#pragma unroll
    for (int jb = 9; jb >= 0; --jb) {
      if (jb >= kb) continue;        // folds at compile time
      const int j = 1 << jb;
      if (jb >= 5) {
        // cross-lane: partner ll ^ (j>>5) (stays in 32-lane group, h preserved)
        const int jl = j >> 5;
        const bool up = (ll & (k >> 5)) != 0;     // e&k  (kb>=6 here)
        const bool tm = up == ((ll & jl) == 0);
#pragma unroll
        for (int t = 0; t < 32; ++t) {
          const float o  = __shfl_xor(v[t], jl, 64);
          const float mn = fminf(v[t], o);
          const float mx = fmaxf(v[t], o);
          v[t] = tm ? mn : mx;
        }
      } else if (kb <= 4) {
        // in-lane, direction compile-time (e&k = t&k since k<=16)
#pragma unroll
        for (int t = 0; t < 32; ++t) {
          if (t & j) continue;
          const int u = t | j;
          const float a0 = v[t], b0 = v[u];
          if ((t & k) != 0) { v[t] = fminf(a0, b0); v[u] = fmaxf(a0, b0); }
          else              { v[t] = fmaxf(a0, b0); v[u] = fminf(a0, b0); }
        }
      } else {
        // in-lane, direction uniform per lane (e&k = (ll & (k>>5)) << 5)
        const bool tm = (ll & (k >> 5)) != 0;
#pragma unroll
        for (int t = 0; t < 32; ++t) {
          if (t & j) continue;
          const int u = t | j;
          const float a0 = v[t], b0 = v[u];
          const float mn = fminf(a0, b0), mx = fmaxf(a0, b0);
          v[t] = tm ? mn : mx;
          v[u] = tm ? mx : mn;
        }
      }
    }
  }

  // dump sorted row to LDS (swizzled 16B chunks), then gather ranks
  {
    float* sb = buf + rloc * NMAPS;
#pragma unroll
    for (int i = 0; i < 8; ++i)
      *(float4*)(sb + swz(8 * ll + i) * 4) =
          make_float4(v[4 * i + 0], v[4 * i + 1], v[4 * i + 2], v[4 * i + 3]);
  }
  __syncthreads();

#pragma unroll
  for (int h2 = 0; h2 < 2; ++h2) {
    const float* sb2 = buf + (wv * 2 + h2) * NMAPS;
    const size_t row2 = (size_t)blockIdx.x * 8 + wv * 2 + h2;
    float ov[4];
#pragma unroll
    for (int q = 0; q < 4; ++q) {
      const int s = rank_of(4 * lane + q);
      ov[q] = sb2[swz(s >> 2) * 4 + (s & 3)];
    }
    *(float4*)(out + row2 * NPOOL + 4 * lane) =
        make_float4(ov[0], ov[1], ov[2], ov[3]);
  }
}

// ================= fallback fused kernel (used only if ws too small) =================
__device__ __forceinline__ bf16x8 ld_frag_f32(const float* p) {
  const float4 a = *(const float4*)p;
  const float4 b = *(const float4*)(p + 4);
  bf16x8 r;
  r[0] = (short)f2bf(a.x); r[1] = (short)f2bf(a.y);
  r[2] = (short)f2bf(a.z); r[3] = (short)f2bf(a.w);
  r[4] = (short)f2bf(b.x); r[5] = (short)f2bf(b.y);
  r[6] = (short)f2bf(b.z); r[7] = (short)f2bf(b.w);
  return r;
}

__device__ __forceinline__ int swz_ex(int row, int col) {
  return col ^ (((col >> 6) & 15) << 1) ^ (row & 1) ^ (((row >> 2) & 1) << 4);
}

__device__ __forceinline__ void sort1024_desc(float (&v)[64], const int li) {
#pragma unroll
  for (int kb = 1; kb <= 10; ++kb) {
    const int k = 1 << kb;
#pragma unroll
    for (int jb = 9; jb >= 0; --jb) {
      if (jb >= kb) continue;
      const int j = 1 << jb;
      if (jb >= 6) {
        const int jl = j >> 6;
        const bool up = (li & (k >> 6)) != 0;
        const bool tm = up == ((li & jl) == 0);
#pragma unroll
        for (int t = 0; t < 64; ++t) {
          const float o  = __shfl_xor(v[t], jl, 64);
          const float mn = fminf(v[t], o);
          const float mx = fmaxf(v[t], o);
          v[t] = tm ? mn : mx;
        }
      } else if (kb <= 5) {
#pragma unroll
        for (int t = 0; t < 64; ++t) {
          if (t & j) continue;
          const int u = t | j;
          const float a0 = v[t], b0 = v[u];
          if ((t & k) != 0) { v[t] = fminf(a0, b0); v[u] = fmaxf(a0, b0); }
          else              { v[t] = fmaxf(a0, b0); v[u] = fminf(a0, b0); }
        }
      } else {
        const bool tm = (li & (k >> 6)) != 0;
#pragma unroll
        for (int t = 0; t < 64; ++t) {
          if (t & j) continue;
          const int u = t | j;
          const float a0 = v[t], b0 = v[u];
          const float mn = fminf(a0, b0), mx = fmaxf(a0, b0);
          v[t] = tm ? mn : mx;
          v[u] = tm ? mx : mn;
        }
      }
    }
  }
}

__global__ __launch_bounds__(512) void corr_pool_kernel(const float* __restrict__ x,
                                                        float* __restrict__ out) {
  __shared__ float ex[16 * 1024];
  const int bid = blockIdx.x;
  const int xcd = bid & 7;
  const int idx = bid >> 3;
  const int b   = xcd + 8 * (idx >> 5);
  const int M0  = (idx & 31) * 32;

  const int tid  = threadIdx.x;
  const int lane = tid & 63;
  const int w    = tid >> 6;
  const int li   = lane & 15;
  const int kh   = lane >> 4;

  const float* __restrict__ Xf = x + (size_t)b * NMAPS * FDIM;

  f32x4 acc[2][8];
#pragma unroll
  for (int a = 0; a < 2; ++a)
#pragma unroll
    for (int n = 0; n < 8; ++n) acc[a][n] = (f32x4){0.f, 0.f, 0.f, 0.f};

#pragma unroll 2
  for (int k0 = 0; k0 < FDIM; k0 += 32) {
    bf16x8 A[2], B[8];
#pragma unroll
    for (int a = 0; a < 2; ++a)
      A[a] = ld_frag_f32(Xf + (M0 + 16 * a + li) * FDIM + k0 + kh * 8);
#pragma unroll
    for (int n = 0; n < 8; ++n)
      B[n] = ld_frag_f32(Xf + (128 * w + 16 * n + li) * FDIM + k0 + kh * 8);
#pragma unroll
    for (int a = 0; a < 2; ++a)
#pragma unroll
      for (int n = 0; n < 8; ++n)
        acc[a][n] = __builtin_amdgcn_mfma_f32_16x16x32_bf16(A[a], B[n], acc[a][n], 0, 0, 0);
  }

  const int R = 4 * w + kh;
  float v[64];
#pragma unroll
  for (int p = 0; p < 2; ++p) {
#pragma unroll
    for (int n = 0; n < 8; ++n) {
      const int col = 128 * w + 16 * n + li;
#pragma unroll
      for (int r = 0; r < 4; ++r) {
        const int rw = 16 * p + 4 * kh + r;
        ex[(rw & 15) * 1024 + swz_ex(rw, col)] = acc[p][n][r] * (1.0f / FDIM);
      }
    }
    __syncthreads();
    if ((w >> 2) == p) {
#pragma unroll
      for (int t = 0; t < 64; ++t)
        v[t] = ex[(R & 15) * 1024 + swz_ex(R, 64 * li + t)];
    }
    __syncthreads();
  }

  sort1024_desc(v, li);

  __syncthreads();
#pragma unroll
  for (int gp = 0; gp < 2; ++gp) {
    if ((w >> 2) == gp) {
#pragma unroll
      for (int t = 0; t < 64; ++t)
        ex[(R & 15) * 1024 + swz_ex(R, 64 * li + t)] = v[t];
    }
    __syncthreads();
    if ((w >> 2) == gp) {
#pragma unroll
      for (int rp = 0; rp < 4; ++rp) {
        const int Rr = 4 * w + rp;
        float ov[4];
#pragma unroll
        for (int q = 0; q < 4; ++q) {
          const int s = rank_of(4 * lane + q);
          ov[q] = ex[(Rr & 15) * 1024 + swz_ex(Rr, s)];
        }
        float* op = out + (size_t)(b * NMAPS + M0 + Rr) * NPOOL;
        *(float4*)(op + 4 * lane) = make_float4(ov[0], ov[1], ov[2], ov[3]);
      }
    }
    __syncthreads();
  }
}

extern "C" void kernel_launch(void* const* d_in, const int* in_sizes, int n_in,
                              void* d_out, int out_size, void* d_ws, size_t ws_size,
                              hipStream_t stream) {
  const float* x = (const float*)d_in[0];
  float* out = (float*)d_out;
  const size_t bf16_bytes = (size_t)NB * NMAPS * FDIM * sizeof(unsigned short);  // 32 MiB
  const size_t corr_bytes = (size_t)NB * NMAPS * NMAPS * sizeof(float);          // 128 MiB

  if (ws_size >= bf16_bytes + corr_bytes) {
    unsigned short* xp = (unsigned short*)d_ws;
    float* C = (float*)((char*)d_ws + bf16_bytes);
    convert_perm_kernel<<<dim3((NB * NMAPS * FDIM) / (256 * 8)), dim3(256), 0, stream>>>(x, xp);
    gemm_kernel<<<dim3(NB * 64), dim3(256), 0, stream>>>(xp, C);
    sort_kernel<<<dim3(NB * NMAPS / 8), dim3(256), 0, stream>>>(C, out);
  } else {
    corr_pool_kernel<<<dim3(NB * 32), dim3(512), 0, stream>>>(x, out);
  }
}